// Round 22
// baseline (232.419 us; speedup 1.0000x reference)
//
#include <hip/hip_runtime.h>
#include <math.h>

// ---------------- problem constants ----------------
#define NRES 64
#define NXY  4096      // 64*64
#define NVOL 262144    // 64^3
#define BB   16
#define WID  32
#define MM   12
#define R24  24

constexpr double DX_d   = 2.0 * 3.14159265358979323846 / 64.0;
constexpr float  INV2DX = (float)(1.0 / (2.0 * DX_d));
constexpr float  INVDX2 = (float)(1.0 / (DX_d * DX_d));
constexpr float  DT_c   = 0.001f;
constexpr float  NU_c   = 0.002f;

// ---------------- workspace layout (float offsets) ----------------
constexpr size_t OFF_FR  = 0;                                  // 24*64 fwd row twiddles (e^{-i})
constexpr size_t OFF_FI  = OFF_FR + (size_t)R24 * NRES;
constexpr size_t OFF_GR  = OFF_FI + (size_t)R24 * NRES;        // 12*64 col twiddles (e^{-i})
constexpr size_t OFF_GI  = OFF_GR + (size_t)MM * NRES;
constexpr size_t OFF_CL  = OFF_GI + (size_t)MM * NRES;         // (unused)
constexpr size_t OFF_HA  = OFF_CL + (size_t)BB * 10 * NXY;     // h buffer A (B,32,64,64)
constexpr size_t OFF_HB  = OFF_HA + (size_t)BB * WID * NXY;    // h buffer B
constexpr size_t OFF_T1R = OFF_HB + (size_t)BB * WID * NXY;    // reused as PT (head partials)
constexpr size_t OFF_T1I = OFF_T1R + (size_t)BB * WID * R24 * NRES;
constexpr size_t OFF_XR  = OFF_T1I + (size_t)BB * WID * R24 * NRES;  // (B,32,288)
constexpr size_t OFF_XI  = OFF_XR + (size_t)BB * WID * R24 * MM;
constexpr size_t OFF_MR  = OFF_XI + (size_t)BB * WID * R24 * MM;     // (unused)
constexpr size_t OFF_MI  = OFF_MR + (size_t)BB * WID * R24 * MM;
constexpr size_t OFF_AR  = OFF_MI + (size_t)BB * WID * R24 * MM;     // (unused)
constexpr size_t OFF_AI  = OFF_AR + (size_t)BB * WID * MM * NRES;
constexpr size_t OFF_H1  = OFF_AI + (size_t)BB * WID * MM * NRES;    // region reused below
constexpr size_t OFF_TAU = OFF_H1 + (size_t)BB * 128 * NXY;          // (unused)
// transposed twiddles [x][24] for k_fwd
constexpr size_t OFF_FRT = OFF_TAU + (size_t)BB * 6 * NXY;
constexpr size_t OFF_FIT = OFF_FRT + (size_t)NRES * R24;

// reuse the H1 region: spectral image + transposed weights
constexpr size_t OFF_SP  = OFF_H1;                                   // (B,32,64,64)
constexpr size_t OFF_W1T = OFF_H1 + (size_t)BB * WID * NXY;          // 128x32
constexpr size_t OFF_CWT = OFF_W1T + 4096;                           // 4 layers x 32o x 32c
constexpr size_t OFF_W0T = OFF_CWT + 4096;                           // 32d x 10c
// head partials PT[2][B][6][4096] reuse T1 region
constexpr size_t OFF_PT  = OFF_T1R;
constexpr size_t PT_STRIDE = (size_t)BB * 6 * NXY;                   // 393216

__device__ __forceinline__ float gelu_fast(float x) {
    float z = 0.79788456080286535588f * (x + 0.044715f * x * x * x);
    float e = __expf(2.0f * z);
    float t = 1.0f - 2.0f / (e + 1.0f);
    return 0.5f * x * (1.0f + t);
}

__device__ __forceinline__ float2 gelu2(float2 v) {
    return make_float2(gelu_fast(v.x), gelu_fast(v.y));
}

// ---------------- K0: twiddle tables + weight transposes ----------------
__global__ void k_setup(const float* __restrict__ fc1w, const float* __restrict__ convw,
                        const float* __restrict__ fc0w, float* __restrict__ ws) {
    int idx = blockIdx.x * 256 + threadIdx.x;   // 34 blocks
    if (idx < R24 * NRES) {
        int r = idx / NRES, x = idx % NRES;
        int kx = (r < MM) ? r : (r + 40);       // rows 0..11 and 52..63
        double ang = -2.0 * 3.14159265358979323846 * (double)(kx * x) / 64.0;
        float cr = (float)cos(ang), ci = (float)sin(ang);
        ws[OFF_FR + idx] = cr;
        ws[OFF_FI + idx] = ci;
        ws[OFF_FRT + (size_t)x * R24 + r] = cr;
        ws[OFF_FIT + (size_t)x * R24 + r] = ci;
    }
    if (idx < MM * NRES) {
        int ky = idx / NRES, y = idx % NRES;
        double ang = -2.0 * 3.14159265358979323846 * (double)(ky * y) / 64.0;
        ws[OFF_GR + idx] = (float)cos(ang);
        ws[OFF_GI + idx] = (float)sin(ang);
    }
    if (idx < 4096) {                           // fc1_w (32,128) -> W1T[e][c]
        int c = idx >> 7, e = idx & 127;
        ws[OFF_W1T + (size_t)e * 32 + c] = fc1w[idx];
    } else if (idx < 8192) {                    // conv_w (4,32,32) -> CWT[l][o][c]
        int j = idx - 4096;
        int l = j >> 10, r = j & 1023;
        int c = r >> 5, o = r & 31;
        ws[OFF_CWT + (size_t)l * 1024 + o * 32 + c] = convw[j];
    } else if (idx < 8512) {                    // fc0_w (10,32) -> W0T[d][c]
        int j = idx - 8192;
        int c = j >> 5, d = j & 31;
        ws[OFF_W0T + (size_t)d * 10 + c] = fc0w[j];
    }
}

// ---------------- K1: fused closure + fc0 lift, 4 z per thread ----------------
__global__ void k_clfc0(const float* __restrict__ v, const float* __restrict__ w0t,
                        const float* __restrict__ bias, float* __restrict__ h) {
    __shared__ __align__(16) float sw[32 * 12];
    __shared__ float sb[32];
    int tid = threadIdx.x;
    for (int i = tid; i < 320; i += 256) {
        int d = i / 10, c = i % 10;
        sw[d * 12 + c] = w0t[i];
    }
    if (tid < 32) sb[tid] = bias[tid];
    __syncthreads();
    int idx = blockIdx.x * 256 + tid;           // B*64*16 = 16384 -> 64 blocks
    int b = idx >> 10;
    int rr = idx & 1023;
    int x = rr >> 4, z0 = (rr & 15) * 4;
    int xp = (x + 1) & 63, xm = (x - 1) & 63;
    float4 cv[10];
    for (int i = 0; i < 3; i++) {
        const float* vb = v + (((size_t)(b * 3 + i)) << 18);
        float4 u4   = *(const float4*)(vb + (size_t)x  * 4096 + 32 * 64 + z0);
        float4 uxp4 = *(const float4*)(vb + (size_t)xp * 4096 + 32 * 64 + z0);
        float4 uxm4 = *(const float4*)(vb + (size_t)xm * 4096 + 32 * 64 + z0);
        float4 uyp4 = *(const float4*)(vb + (size_t)x  * 4096 + 33 * 64 + z0);
        float4 uym4 = *(const float4*)(vb + (size_t)x  * 4096 + 31 * 64 + z0);
        cv[i * 3 + 0] = make_float4((uxp4.x - uxm4.x) * INV2DX, (uxp4.y - uxm4.y) * INV2DX,
                                    (uxp4.z - uxm4.z) * INV2DX, (uxp4.w - uxm4.w) * INV2DX);
        cv[i * 3 + 1] = make_float4((uyp4.x - uym4.x) * INV2DX, (uyp4.y - uym4.y) * INV2DX,
                                    (uyp4.z - uym4.z) * INV2DX, (uyp4.w - uym4.w) * INV2DX);
        cv[i * 3 + 2] = make_float4(0.1f * u4.x, 0.1f * u4.y, 0.1f * u4.z, 0.1f * u4.w);
    }
    float4 ss = make_float4(0.f, 0.f, 0.f, 0.f);
    for (int i = 0; i < 3; i++)
        for (int j = 0; j < 3; j++) {
            float4 a = cv[i * 3 + j], bt = cv[j * 3 + i];
            float sx = 0.5f * (a.x + bt.x), sy = 0.5f * (a.y + bt.y);
            float sz = 0.5f * (a.z + bt.z), sw_ = 0.5f * (a.w + bt.w);
            ss.x += sx * sx; ss.y += sy * sy; ss.z += sz * sz; ss.w += sw_ * sw_;
        }
    cv[9] = make_float4(sqrtf(2.f * ss.x), sqrtf(2.f * ss.y),
                        sqrtf(2.f * ss.z), sqrtf(2.f * ss.w));
    float* hp = h + (size_t)b * WID * NXY + (size_t)x * 64 + z0;
#pragma unroll
    for (int d = 0; d < 32; d++) {
        float4 acc = make_float4(sb[d], sb[d], sb[d], sb[d]);
#pragma unroll
        for (int c = 0; c < 10; c++) {
            float w = sw[d * 12 + c];
            acc.x += w * cv[c].x; acc.y += w * cv[c].y;
            acc.z += w * cv[c].z; acc.w += w * cv[c].w;
        }
        *(float4*)(hp + (size_t)d * NXY) = acc;
    }
}

// ---------------- K3: fused forward DFT, r-split across 2 blocks per (b,c) ----------------
__global__ void k_fwd(const float* __restrict__ h, const float* __restrict__ ws,
                      float* __restrict__ xr, float* __restrict__ xi) {
    __shared__ __align__(16) float sh[4096];
    __shared__ float st1r[12 * 65];
    __shared__ float st1i[12 * 65];
    __shared__ float sgr[12 * 64];
    __shared__ float sgi[12 * 64];
    int tid = threadIdx.x;
    int blk = blockIdx.x;                       // grid = 1024
    int bc = blk >> 1, half = blk & 1;
    int rbase = half * 12;
    const float4* hp4 = (const float4*)(h + (size_t)bc * NXY);
    float4* sh4 = (float4*)sh;
#pragma unroll
    for (int i = 0; i < 4; i++) sh4[tid + 256 * i] = hp4[tid + 256 * i];
    {
        const float* GRg = ws + OFF_GR;
        const float* GIg = ws + OFF_GI;
#pragma unroll
        for (int i = 0; i < 3; i++) {
            sgr[tid + 256 * i] = GRg[tid + 256 * i];
            sgi[tid + 256 * i] = GIg[tid + 256 * i];
        }
    }
    __syncthreads();
    const float* FRT = ws + OFF_FRT;
    const float* FIT = ws + OFF_FIT;
#pragma unroll
    for (int it = 0; it < 3; it++) {
        int point = it * 256 + tid;             // 0..767 = 12 r x 64 y
        int y = point & 63;
        int rl = __builtin_amdgcn_readfirstlane(point >> 6);   // 0..11
        int rg = rbase + rl;
        float ar = 0.f, ai = 0.f;
#pragma unroll 16
        for (int x = 0; x < 64; x++) {
            float hv = sh[x * 64 + y];
            ar += hv * FRT[x * R24 + rg];
            ai += hv * FIT[x * R24 + rg];
        }
        st1r[rl * 65 + y] = ar;
        st1i[rl * 65 + y] = ai;
    }
    __syncthreads();
    if (tid < 144) {                            // 12 r x 12 ky
        int rl = tid / 12, ky = tid - rl * 12;
        const float* Gr = sgr + ky * 64;
        const float* Gi = sgi + ky * 64;
        float ar = 0.f, ai = 0.f;
#pragma unroll 16
        for (int yy = 0; yy < 64; yy++) {
            float a = st1r[rl * 65 + yy], b = st1i[rl * 65 + yy];
            float c = Gr[yy], d = Gi[yy];
            ar += a * c - b * d;
            ai += a * d + b * c;
        }
        size_t outp = (size_t)bc * 288 + (size_t)(rbase + rl) * 12 + ky;
        xr[outp] = ar;
        xi[outp] = ai;
    }
}

// ---------------- K5: fused spectral mix + inverse DFT -> sp ; one block per (b,o) ---------
// 576 threads; spec phase i-sum split across 2 threads for 2x memory-level parallelism.
__global__ void __launch_bounds__(576, 2)
k_specinv(const float* __restrict__ xr, const float* __restrict__ xi,
          const float* __restrict__ w1, const float* __restrict__ w2,
          const float* __restrict__ ws, float* __restrict__ sp) {
    __shared__ float spr[2][288];
    __shared__ float spi[2][288];
    __shared__ float sm_r[288];
    __shared__ float sm_i[288];
    __shared__ float sa_r[12 * 64];
    __shared__ float sa_i[12 * 64];
    __shared__ float sgr[12 * 64];
    __shared__ float sgi[12 * 64];
    int tid = threadIdx.x;                      // 0..575
    int bo = blockIdx.x;                        // grid = 512
    int o = bo & 31, b = bo >> 5;
    {
        const float* GRg = ws + OFF_GR;
        const float* GIg = ws + OFF_GI;
#pragma unroll
        for (int i = 0; i < 2; i++) {
            int j = tid + 576 * i;
            if (j < 768) {
                sgr[j] = GRg[j];
                sgi[j] = GIg[j];
            }
        }
    }
    // spec phase: M[m] = sum_i X[b,i,m]*W[i,o,m]; thread (m, ih) sums 16 i's
    {
        int ih = (tid >= 288) ? 1 : 0;
        int m = tid - ih * 288;
        int r = m / 12;
        int kxy = (r < MM) ? m : (m - 144);
        const float* wp = ((r < MM) ? w1 : w2) + ((size_t)o * 144 + kxy) * 2
                          + (size_t)(ih * 16) * 9216;
        size_t xbase = (size_t)b * 32 * 288 + (size_t)(ih * 16) * 288 + m;
        float ar = 0.f, ai = 0.f;
#pragma unroll 8
        for (int i = 0; i < 16; i++) {
            float a   = xr[xbase + (size_t)i * 288];
            float bb  = xi[xbase + (size_t)i * 288];
            float wr_ = wp[(size_t)i * 9216];
            float wi_ = wp[(size_t)i * 9216 + 1];
            ar += a * wr_ - bb * wi_;
            ai += a * wi_ + bb * wr_;
        }
        spr[ih][m] = ar;
        spi[ih][m] = ai;
    }
    __syncthreads();
    if (tid < 288) {
        sm_r[tid] = spr[0][tid] + spr[1][tid];
        sm_i[tid] = spi[0][tid] + spi[1][tid];
    }
    __syncthreads();
    const float* FR = ws + OFF_FR;
    const float* FI = ws + OFF_FI;
    // inv phase 1: A[ky][x] = sum_r M[r][ky] * e^{+i 2pi kx x / 64}  (768 items)
#pragma unroll
    for (int it = 0; it < 2; it++) {
        int point = it * 576 + tid;
        if (point < 768) {
            int x = point & 63;
            int ky = __builtin_amdgcn_readfirstlane(point >> 6);
            float ar = 0.f, ai = 0.f;
#pragma unroll 8
            for (int r = 0; r < 24; r++) {
                float a = sm_r[r * 12 + ky], bb = sm_i[r * 12 + ky];
                float c = FR[r * 64 + x], d = FI[r * 64 + x];   // cos, -sin
                ar += a * c + bb * d;
                ai += bb * c - a * d;
            }
            sa_r[ky * 64 + x] = ar;
            sa_i[ky * 64 + x] = ai;
        }
    }
    __syncthreads();
    float* spb = sp + (size_t)bo * NXY;
    // inv phase 2: c2r over ky — all operands in LDS (4096 px)
#pragma unroll
    for (int it = 0; it < 8; it++) {
        int px = it * 576 + tid;
        if (px < 4096) {
            int y = px & 63;
            int x = __builtin_amdgcn_readfirstlane(px >> 6);
            float s = sa_r[x];                  // ky=0: Re only
#pragma unroll
            for (int ky = 1; ky < 12; ky++) {
                float gr = sgr[ky * 64 + y];
                float gi = sgi[ky * 64 + y];
                s += 2.0f * (sa_r[ky * 64 + x] * gr + sa_i[ky * 64 + x] * gi);
            }
            spb[px] = s * (1.0f / 4096.0f);
        }
    }
}

// ---------------- K7: 1x1 conv, 2 px per thread, o-split across 2 blocks ----------------
template <int DOGELU>
__global__ void __launch_bounds__(256, 2)
k_convg(const float* __restrict__ sp, const float* __restrict__ hin,
        const float* __restrict__ cwt, const float* __restrict__ cb,
        float* __restrict__ hout) {
    __shared__ __align__(16) float scw[1024];
    __shared__ float scb[32];
    int tid = threadIdx.x;
#pragma unroll
    for (int i = 0; i < 4; i++) scw[tid + 256 * i] = cwt[tid + 256 * i];
    if (tid < 32) scb[tid] = cb[tid];
    __syncthreads();
    int wid = tid >> 6, lane = tid & 63;
    int blk = blockIdx.x;                       // grid = 1024
    int osec = blk & 1;
    int q = (blk >> 1) * 64 + lane;             // pair index 0..32767
    int b = q >> 11, p = (q & 2047) * 2;
    const float* hp = hin + (size_t)b * WID * NXY + p;
    float2 hv[32];
#pragma unroll
    for (int c = 0; c < 32; c++) hv[c] = *(const float2*)(hp + (size_t)c * NXY);
    const float* spp = sp + (size_t)b * WID * NXY + p;
    float* op = hout + (size_t)b * WID * NXY + p;
#pragma unroll
    for (int j = 0; j < 4; j++) {
        int o = osec * 16 + wid * 4 + j;
        const float4* wr = (const float4*)&scw[o * 32];
        float2 d = make_float2(scb[o], scb[o]);
#pragma unroll
        for (int q8 = 0; q8 < 8; q8++) {
            float4 w = wr[q8];
            float2 h0 = hv[q8 * 4], h1 = hv[q8 * 4 + 1], h2 = hv[q8 * 4 + 2], h3 = hv[q8 * 4 + 3];
            d.x += w.x * h0.x + w.y * h1.x + w.z * h2.x + w.w * h3.x;
            d.y += w.x * h0.y + w.y * h1.y + w.z * h2.y + w.w * h3.y;
        }
        float2 spv = *(const float2*)(spp + (size_t)o * NXY);
        float2 v2 = make_float2(d.x + spv.x, d.y + spv.y);
        if (DOGELU) v2 = gelu2(v2);
        *(float2*)(op + (size_t)o * NXY) = v2;
    }
}

// ---------------- K8: fused head, 2 px per thread, e-split across 2 blocks ----------
__global__ void __launch_bounds__(256, 2)
k_head(const float* __restrict__ h, const float* __restrict__ w1t,
       const float* __restrict__ b1, const float* __restrict__ w2,
       float* __restrict__ pt) {
    __shared__ __align__(16) float sw1[64 * 32];
    __shared__ float sb1l[64];
    __shared__ __align__(16) float sw2l[64 * 8];
    __shared__ __align__(8) float2 red[4][6][64];
    int tid = threadIdx.x;
    int blk = blockIdx.x;                       // grid = 1024
    int esec = blk & 1;
    int ebase = esec * 64;
#pragma unroll
    for (int i = 0; i < 8; i++) sw1[tid + 256 * i] = w1t[(size_t)ebase * 32 + tid + 256 * i];
    if (tid < 64) sb1l[tid] = b1[ebase + tid];
    for (int i = tid; i < 384; i += 256) {      // this section's w2 rows -> padded (64x8)
        int e = i / 6, t = i - e * 6;
        sw2l[e * 8 + t] = w2[(size_t)(ebase + e) * 6 + t];
    }
    __syncthreads();
    int wid = tid >> 6, lane = tid & 63;
    int q = (blk >> 1) * 64 + lane;             // pair index 0..32767
    int b = q >> 11, p = (q & 2047) * 2;
    const float* hp = h + (size_t)b * WID * NXY + p;
    float2 hv[32];
#pragma unroll
    for (int c = 0; c < 32; c++) hv[c] = *(const float2*)(hp + (size_t)c * NXY);
    float2 acc[6];
#pragma unroll
    for (int t = 0; t < 6; t++) acc[t] = make_float2(0.f, 0.f);
#pragma unroll 4
    for (int jj = 0; jj < 16; jj++) {
        int el = wid * 16 + jj;                 // local e 0..63
        const float4* wr = (const float4*)&sw1[el * 32];
        float2 d = make_float2(sb1l[el], sb1l[el]);
#pragma unroll
        for (int q8 = 0; q8 < 8; q8++) {
            float4 w = wr[q8];
            float2 h0 = hv[q8 * 4], h1 = hv[q8 * 4 + 1], h2 = hv[q8 * 4 + 2], h3 = hv[q8 * 4 + 3];
            d.x += w.x * h0.x + w.y * h1.x + w.z * h2.x + w.w * h3.x;
            d.y += w.x * h0.y + w.y * h1.y + w.z * h2.y + w.w * h3.y;
        }
        float2 g = gelu2(d);
        const float4* w2r = (const float4*)&sw2l[el * 8];
        float4 wa = w2r[0], wb = w2r[1];
        acc[0].x += g.x * wa.x; acc[0].y += g.y * wa.x;
        acc[1].x += g.x * wa.y; acc[1].y += g.y * wa.y;
        acc[2].x += g.x * wa.z; acc[2].y += g.y * wa.z;
        acc[3].x += g.x * wa.w; acc[3].y += g.y * wa.w;
        acc[4].x += g.x * wb.x; acc[4].y += g.y * wb.x;
        acc[5].x += g.x * wb.y; acc[5].y += g.y * wb.y;
    }
#pragma unroll
    for (int t = 0; t < 6; t++) red[wid][t][lane] = acc[t];
    __syncthreads();
    if (wid == 0) {
        float* pb = pt + (size_t)esec * PT_STRIDE + (size_t)b * 6 * NXY + p;
#pragma unroll
        for (int t = 0; t < 6; t++) {
            float2 r0 = red[0][t][lane], r1 = red[1][t][lane];
            float2 r2 = red[2][t][lane], r3 = red[3][t][lane];
            float2 s = make_float2(r0.x + r1.x + r2.x + r3.x,
                                   r0.y + r1.y + r2.y + r3.y);
            *(float2*)(pb + (size_t)t * NXY) = s;
        }
    }
}

// ---------------- K10: NS update; sums head partials inline (fc2 bias cancels in diffs) ----
__global__ void __launch_bounds__(256, 2)
k_ns(const float* __restrict__ v, const float* __restrict__ pt,
     float* __restrict__ out) {
    int idx = blockIdx.x * 256 + threadIdx.x;   // 4096 blocks
    int b = idx >> 16;
    int r = idx & 65535;
    int x = r >> 10;
    int y = (r >> 4) & 63;
    int z0 = (r & 15) * 4;
    int xp = (x + 1) & 63, xm = (x - 1) & 63;
    int yp = (y + 1) & 63, ym = (y - 1) & 63;
    int zm = (z0 - 1) & 63, zp = (z0 + 4) & 63;

    float4 u[3], gx[3], gy[3], gz[3], lap[3];
    for (int i = 0; i < 3; i++) {
        const float* vb = v + (((size_t)(b * 3 + i)) << 18);
        const float* row = vb + (size_t)x * 4096 + (size_t)y * 64;
        float4 c4   = *(const float4*)(row + z0);
        float  czm  = row[zm];
        float  czp  = row[zp];
        float4 xp4  = *(const float4*)(vb + (size_t)xp * 4096 + (size_t)y * 64 + z0);
        float4 xm4  = *(const float4*)(vb + (size_t)xm * 4096 + (size_t)y * 64 + z0);
        float4 yp4  = *(const float4*)(vb + (size_t)x * 4096 + (size_t)yp * 64 + z0);
        float4 ym4  = *(const float4*)(vb + (size_t)x * 4096 + (size_t)ym * 64 + z0);
        u[i] = c4;
        gx[i] = make_float4((xp4.x - xm4.x) * INV2DX, (xp4.y - xm4.y) * INV2DX,
                            (xp4.z - xm4.z) * INV2DX, (xp4.w - xm4.w) * INV2DX);
        gy[i] = make_float4((yp4.x - ym4.x) * INV2DX, (yp4.y - ym4.y) * INV2DX,
                            (yp4.z - ym4.z) * INV2DX, (yp4.w - ym4.w) * INV2DX);
        gz[i] = make_float4((c4.y - czm) * INV2DX, (c4.z - c4.x) * INV2DX,
                            (c4.w - c4.y) * INV2DX, (czp - c4.z) * INV2DX);
        lap[i] = make_float4(
            (xp4.x + xm4.x + yp4.x + ym4.x + czm  + c4.y - 6.f * c4.x) * INVDX2,
            (xp4.y + xm4.y + yp4.y + ym4.y + c4.x + c4.z - 6.f * c4.y) * INVDX2,
            (xp4.z + xm4.z + yp4.z + ym4.z + c4.y + c4.w - 6.f * c4.z) * INVDX2,
            (xp4.w + xm4.w + yp4.w + ym4.w + c4.z + czp  - 6.f * c4.w) * INVDX2);
    }
    const float* p0 = pt + (size_t)b * 6 * NXY;
    const float* p1 = p0 + PT_STRIDE;
    int pxp = xp * 64 + y, pxm = xm * 64 + y, pyp = x * 64 + yp, pym = x * 64 + ym;
#define TV(t, pos) (p0[(size_t)(t) * NXY + (pos)] + p1[(size_t)(t) * NXY + (pos)])
    float d0 = (TV(0, pxp) - TV(0, pxm)) * INV2DX + (TV(3, pyp) - TV(3, pym)) * INV2DX;
    float d1 = (TV(3, pxp) - TV(3, pxm)) * INV2DX + (TV(1, pyp) - TV(1, pym)) * INV2DX;
    float d2 = (TV(4, pxp) - TV(4, pxm)) * INV2DX + (TV(5, pyp) - TV(5, pym)) * INV2DX;
#undef TV

    size_t so = ((size_t)b * 3) * NVOL + (size_t)x * 4096 + (size_t)y * 64 + z0;
#pragma unroll
    for (int i = 0; i < 3; i++) {
        float dti = (i == 0) ? d0 : (i == 1) ? d1 : d2;
        float4 conv = make_float4(
            u[0].x * ((i==0)?gx[0].x:(i==1)?gy[0].x:gz[0].x) + u[1].x * ((i==0)?gx[1].x:(i==1)?gy[1].x:gz[1].x) + u[2].x * ((i==0)?gx[2].x:(i==1)?gy[2].x:gz[2].x),
            u[0].y * ((i==0)?gx[0].y:(i==1)?gy[0].y:gz[0].y) + u[1].y * ((i==0)?gx[1].y:(i==1)?gy[1].y:gz[1].y) + u[2].y * ((i==0)?gx[2].y:(i==1)?gy[2].y:gz[2].y),
            u[0].z * ((i==0)?gx[0].z:(i==1)?gy[0].z:gz[0].z) + u[1].z * ((i==0)?gx[1].z:(i==1)?gy[1].z:gz[1].z) + u[2].z * ((i==0)?gx[2].z:(i==1)?gy[2].z:gz[2].z),
            u[0].w * ((i==0)?gx[0].w:(i==1)?gy[0].w:gz[0].w) + u[1].w * ((i==0)?gx[1].w:(i==1)?gy[1].w:gz[1].w) + u[2].w * ((i==0)?gx[2].w:(i==1)?gy[2].w:gz[2].w));
        float4 res = make_float4(
            u[i].x + DT_c * (-conv.x + NU_c * lap[i].x + dti),
            u[i].y + DT_c * (-conv.y + NU_c * lap[i].y + dti),
            u[i].z + DT_c * (-conv.z + NU_c * lap[i].z + dti),
            u[i].w + DT_c * (-conv.w + NU_c * lap[i].w + dti));
        *(float4*)(out + so + (size_t)i * NVOL) = res;
    }
}

extern "C" void kernel_launch(void* const* d_in, const int* in_sizes, int n_in,
                              void* d_out, int out_size, void* d_ws, size_t ws_size,
                              hipStream_t stream) {
    const float* vel   = (const float*)d_in[0];
    const float* fc0w  = (const float*)d_in[1];
    const float* fc0b  = (const float*)d_in[2];
    const float* sw1   = (const float*)d_in[3];
    const float* sw2   = (const float*)d_in[4];
    const float* convw = (const float*)d_in[5];
    const float* convb = (const float*)d_in[6];
    const float* fc1w  = (const float*)d_in[7];
    const float* fc1b  = (const float*)d_in[8];
    const float* fc2w  = (const float*)d_in[9];
    float* ws  = (float*)d_ws;
    float* out = (float*)d_out;

    k_setup<<<34, 256, 0, stream>>>(fc1w, convw, fc0w, ws);
    k_clfc0<<<64, 256, 0, stream>>>(vel, ws + OFF_W0T, fc0b, ws + OFF_HA);

    float* hcur  = ws + OFF_HA;
    float* hnext = ws + OFF_HB;
    for (int l = 0; l < 4; l++) {
        const float* wl1 = sw1 + (size_t)l * WID * WID * MM * MM * 2;
        const float* wl2 = sw2 + (size_t)l * WID * WID * MM * MM * 2;
        const float* cwl = ws + OFF_CWT + (size_t)l * 1024;
        const float* cbl = convb + (size_t)l * 32;
        k_fwd<<<1024, 256, 0, stream>>>(hcur, ws, ws + OFF_XR, ws + OFF_XI);
        k_specinv<<<512, 576, 0, stream>>>(ws + OFF_XR, ws + OFF_XI, wl1, wl2, ws, ws + OFF_SP);
        if (l < 3)
            k_convg<1><<<1024, 256, 0, stream>>>(ws + OFF_SP, hcur, cwl, cbl, hnext);
        else
            k_convg<0><<<1024, 256, 0, stream>>>(ws + OFF_SP, hcur, cwl, cbl, hnext);
        float* tmp = hcur; hcur = hnext; hnext = tmp;
    }

    k_head<<<1024, 256, 0, stream>>>(hcur, ws + OFF_W1T, fc1b, fc2w, ws + OFF_PT);
    k_ns<<<4096, 256, 0, stream>>>(vel, ws + OFF_PT, out);
}

// Round 23
// 225.800 us; speedup vs baseline: 1.0293x; 1.0293x over previous
//
#include <hip/hip_runtime.h>
#include <math.h>

// ---------------- problem constants ----------------
#define NRES 64
#define NXY  4096      // 64*64
#define NVOL 262144    // 64^3
#define BB   16
#define WID  32
#define MM   12
#define R24  24

constexpr double DX_d   = 2.0 * 3.14159265358979323846 / 64.0;
constexpr float  INV2DX = (float)(1.0 / (2.0 * DX_d));
constexpr float  INVDX2 = (float)(1.0 / (DX_d * DX_d));
constexpr float  DT_c   = 0.001f;
constexpr float  NU_c   = 0.002f;

// ---------------- workspace layout (float offsets) ----------------
constexpr size_t OFF_FR  = 0;                                  // 24*64 fwd row twiddles (e^{-i})
constexpr size_t OFF_FI  = OFF_FR + (size_t)R24 * NRES;
constexpr size_t OFF_GR  = OFF_FI + (size_t)R24 * NRES;        // 12*64 col twiddles (e^{-i})
constexpr size_t OFF_GI  = OFF_GR + (size_t)MM * NRES;
constexpr size_t OFF_CL  = OFF_GI + (size_t)MM * NRES;         // (unused)
constexpr size_t OFF_HA  = OFF_CL + (size_t)BB * 10 * NXY;     // h buffer A (B,32,64,64)
constexpr size_t OFF_HB  = OFF_HA + (size_t)BB * WID * NXY;    // h buffer B
constexpr size_t OFF_T1R = OFF_HB + (size_t)BB * WID * NXY;    // reused as PT (head partials)
constexpr size_t OFF_T1I = OFF_T1R + (size_t)BB * WID * R24 * NRES;
constexpr size_t OFF_XR  = OFF_T1I + (size_t)BB * WID * R24 * NRES;  // (B,32,288)
constexpr size_t OFF_XI  = OFF_XR + (size_t)BB * WID * R24 * MM;
constexpr size_t OFF_MR  = OFF_XI + (size_t)BB * WID * R24 * MM;     // (unused)
constexpr size_t OFF_MI  = OFF_MR + (size_t)BB * WID * R24 * MM;
constexpr size_t OFF_AR  = OFF_MI + (size_t)BB * WID * R24 * MM;     // (unused)
constexpr size_t OFF_AI  = OFF_AR + (size_t)BB * WID * MM * NRES;
constexpr size_t OFF_H1  = OFF_AI + (size_t)BB * WID * MM * NRES;    // region reused below
constexpr size_t OFF_TAU = OFF_H1 + (size_t)BB * 128 * NXY;          // (unused)
// transposed twiddles [x][24] for k_fwd
constexpr size_t OFF_FRT = OFF_TAU + (size_t)BB * 6 * NXY;
constexpr size_t OFF_FIT = OFF_FRT + (size_t)NRES * R24;

// reuse the H1 region: spectral image + transposed weights
constexpr size_t OFF_SP  = OFF_H1;                                   // (B,32,64,64)
constexpr size_t OFF_W1T = OFF_H1 + (size_t)BB * WID * NXY;          // 128x32
constexpr size_t OFF_CWT = OFF_W1T + 4096;                           // 4 layers x 32o x 32c
constexpr size_t OFF_W0T = OFF_CWT + 4096;                           // 32d x 10c
// head partials PT[2][B][6][4096] reuse T1 region
constexpr size_t OFF_PT  = OFF_T1R;
constexpr size_t PT_STRIDE = (size_t)BB * 6 * NXY;                   // 393216

__device__ __forceinline__ float gelu_fast(float x) {
    float z = 0.79788456080286535588f * (x + 0.044715f * x * x * x);
    float e = __expf(2.0f * z);
    float t = 1.0f - 2.0f / (e + 1.0f);
    return 0.5f * x * (1.0f + t);
}

__device__ __forceinline__ float2 gelu2(float2 v) {
    return make_float2(gelu_fast(v.x), gelu_fast(v.y));
}

// ---------------- K0: twiddle tables + weight transposes ----------------
__global__ void k_setup(const float* __restrict__ fc1w, const float* __restrict__ convw,
                        const float* __restrict__ fc0w, float* __restrict__ ws) {
    int idx = blockIdx.x * 256 + threadIdx.x;   // 34 blocks
    if (idx < R24 * NRES) {
        int r = idx / NRES, x = idx % NRES;
        int kx = (r < MM) ? r : (r + 40);       // rows 0..11 and 52..63
        double ang = -2.0 * 3.14159265358979323846 * (double)(kx * x) / 64.0;
        float cr = (float)cos(ang), ci = (float)sin(ang);
        ws[OFF_FR + idx] = cr;
        ws[OFF_FI + idx] = ci;
        ws[OFF_FRT + (size_t)x * R24 + r] = cr;
        ws[OFF_FIT + (size_t)x * R24 + r] = ci;
    }
    if (idx < MM * NRES) {
        int ky = idx / NRES, y = idx % NRES;
        double ang = -2.0 * 3.14159265358979323846 * (double)(ky * y) / 64.0;
        ws[OFF_GR + idx] = (float)cos(ang);
        ws[OFF_GI + idx] = (float)sin(ang);
    }
    if (idx < 4096) {                           // fc1_w (32,128) -> W1T[e][c]
        int c = idx >> 7, e = idx & 127;
        ws[OFF_W1T + (size_t)e * 32 + c] = fc1w[idx];
    } else if (idx < 8192) {                    // conv_w (4,32,32) -> CWT[l][o][c]
        int j = idx - 4096;
        int l = j >> 10, r = j & 1023;
        int c = r >> 5, o = r & 31;
        ws[OFF_CWT + (size_t)l * 1024 + o * 32 + c] = convw[j];
    } else if (idx < 8512) {                    // fc0_w (10,32) -> W0T[d][c]
        int j = idx - 8192;
        int c = j >> 5, d = j & 31;
        ws[OFF_W0T + (size_t)d * 10 + c] = fc0w[j];
    }
}

// ---------------- K1: fused closure + fc0 lift, 4 z per thread ----------------
__global__ void k_clfc0(const float* __restrict__ v, const float* __restrict__ w0t,
                        const float* __restrict__ bias, float* __restrict__ h) {
    __shared__ __align__(16) float sw[32 * 12];
    __shared__ float sb[32];
    int tid = threadIdx.x;
    for (int i = tid; i < 320; i += 256) {
        int d = i / 10, c = i % 10;
        sw[d * 12 + c] = w0t[i];
    }
    if (tid < 32) sb[tid] = bias[tid];
    __syncthreads();
    int idx = blockIdx.x * 256 + tid;           // B*64*16 = 16384 -> 64 blocks
    int b = idx >> 10;
    int rr = idx & 1023;
    int x = rr >> 4, z0 = (rr & 15) * 4;
    int xp = (x + 1) & 63, xm = (x - 1) & 63;
    float4 cv[10];
    for (int i = 0; i < 3; i++) {
        const float* vb = v + (((size_t)(b * 3 + i)) << 18);
        float4 u4   = *(const float4*)(vb + (size_t)x  * 4096 + 32 * 64 + z0);
        float4 uxp4 = *(const float4*)(vb + (size_t)xp * 4096 + 32 * 64 + z0);
        float4 uxm4 = *(const float4*)(vb + (size_t)xm * 4096 + 32 * 64 + z0);
        float4 uyp4 = *(const float4*)(vb + (size_t)x  * 4096 + 33 * 64 + z0);
        float4 uym4 = *(const float4*)(vb + (size_t)x  * 4096 + 31 * 64 + z0);
        cv[i * 3 + 0] = make_float4((uxp4.x - uxm4.x) * INV2DX, (uxp4.y - uxm4.y) * INV2DX,
                                    (uxp4.z - uxm4.z) * INV2DX, (uxp4.w - uxm4.w) * INV2DX);
        cv[i * 3 + 1] = make_float4((uyp4.x - uym4.x) * INV2DX, (uyp4.y - uym4.y) * INV2DX,
                                    (uyp4.z - uym4.z) * INV2DX, (uyp4.w - uym4.w) * INV2DX);
        cv[i * 3 + 2] = make_float4(0.1f * u4.x, 0.1f * u4.y, 0.1f * u4.z, 0.1f * u4.w);
    }
    float4 ss = make_float4(0.f, 0.f, 0.f, 0.f);
    for (int i = 0; i < 3; i++)
        for (int j = 0; j < 3; j++) {
            float4 a = cv[i * 3 + j], bt = cv[j * 3 + i];
            float sx = 0.5f * (a.x + bt.x), sy = 0.5f * (a.y + bt.y);
            float sz = 0.5f * (a.z + bt.z), sw_ = 0.5f * (a.w + bt.w);
            ss.x += sx * sx; ss.y += sy * sy; ss.z += sz * sz; ss.w += sw_ * sw_;
        }
    cv[9] = make_float4(sqrtf(2.f * ss.x), sqrtf(2.f * ss.y),
                        sqrtf(2.f * ss.z), sqrtf(2.f * ss.w));
    float* hp = h + (size_t)b * WID * NXY + (size_t)x * 64 + z0;
#pragma unroll
    for (int d = 0; d < 32; d++) {
        float4 acc = make_float4(sb[d], sb[d], sb[d], sb[d]);
#pragma unroll
        for (int c = 0; c < 10; c++) {
            float w = sw[d * 12 + c];
            acc.x += w * cv[c].x; acc.y += w * cv[c].y;
            acc.z += w * cv[c].z; acc.w += w * cv[c].w;
        }
        *(float4*)(hp + (size_t)d * NXY) = acc;
    }
}

// ---------------- K3: fused forward DFT, r-split across 2 blocks per (b,c) ----------------
__global__ void k_fwd(const float* __restrict__ h, const float* __restrict__ ws,
                      float* __restrict__ xr, float* __restrict__ xi) {
    __shared__ __align__(16) float sh[4096];
    __shared__ float st1r[12 * 65];
    __shared__ float st1i[12 * 65];
    __shared__ float sgr[12 * 64];
    __shared__ float sgi[12 * 64];
    int tid = threadIdx.x;
    int blk = blockIdx.x;                       // grid = 1024
    int bc = blk >> 1, half = blk & 1;
    int rbase = half * 12;
    const float4* hp4 = (const float4*)(h + (size_t)bc * NXY);
    float4* sh4 = (float4*)sh;
#pragma unroll
    for (int i = 0; i < 4; i++) sh4[tid + 256 * i] = hp4[tid + 256 * i];
    {
        const float* GRg = ws + OFF_GR;
        const float* GIg = ws + OFF_GI;
#pragma unroll
        for (int i = 0; i < 3; i++) {
            sgr[tid + 256 * i] = GRg[tid + 256 * i];
            sgi[tid + 256 * i] = GIg[tid + 256 * i];
        }
    }
    __syncthreads();
    const float* FRT = ws + OFF_FRT;
    const float* FIT = ws + OFF_FIT;
#pragma unroll
    for (int it = 0; it < 3; it++) {
        int point = it * 256 + tid;             // 0..767 = 12 r x 64 y
        int y = point & 63;
        int rl = __builtin_amdgcn_readfirstlane(point >> 6);   // 0..11
        int rg = rbase + rl;
        float ar = 0.f, ai = 0.f;
#pragma unroll 16
        for (int x = 0; x < 64; x++) {
            float hv = sh[x * 64 + y];
            ar += hv * FRT[x * R24 + rg];
            ai += hv * FIT[x * R24 + rg];
        }
        st1r[rl * 65 + y] = ar;
        st1i[rl * 65 + y] = ai;
    }
    __syncthreads();
    if (tid < 144) {                            // 12 r x 12 ky
        int rl = tid / 12, ky = tid - rl * 12;
        const float* Gr = sgr + ky * 64;
        const float* Gi = sgi + ky * 64;
        float ar = 0.f, ai = 0.f;
#pragma unroll 16
        for (int yy = 0; yy < 64; yy++) {
            float a = st1r[rl * 65 + yy], b = st1i[rl * 65 + yy];
            float c = Gr[yy], d = Gi[yy];
            ar += a * c - b * d;
            ai += a * d + b * c;
        }
        size_t outp = (size_t)bc * 288 + (size_t)(rbase + rl) * 12 + ky;
        xr[outp] = ar;
        xi[outp] = ai;
    }
}

// ---------------- K5: fused spectral mix + inverse DFT -> sp ; one block per (b,o) ---------
// 512 threads: same traffic, double the waves/CU for latency hiding.
__global__ void __launch_bounds__(512, 2)
k_specinv(const float* __restrict__ xr, const float* __restrict__ xi,
          const float* __restrict__ w1, const float* __restrict__ w2,
          const float* __restrict__ ws, float* __restrict__ sp) {
    __shared__ float sm_r[288];
    __shared__ float sm_i[288];
    __shared__ float sa_r[12 * 64];
    __shared__ float sa_i[12 * 64];
    __shared__ float sgr[12 * 64];
    __shared__ float sgi[12 * 64];
    int tid = threadIdx.x;                      // 0..511
    int bo = blockIdx.x;                        // grid = 512
    int o = bo & 31, b = bo >> 5;
    {
        const float* GRg = ws + OFF_GR;
        const float* GIg = ws + OFF_GI;
#pragma unroll
        for (int i = 0; i < 2; i++) {
            int j = tid + 512 * i;
            if (j < 768) {
                sgr[j] = GRg[j];
                sgi[j] = GIg[j];
            }
        }
    }
    // spec phase: M[m] = sum_i X[b,i,m] * W[i,o,m]  (288 items, single pass)
    if (tid < 288) {
        int m = tid;
        int r = m / 12;
        int kxy = (r < MM) ? m : (m - 144);
        const float* wp = ((r < MM) ? w1 : w2) + ((size_t)o * 144 + kxy) * 2;
        size_t xbase = (size_t)b * 32 * 288 + m;
        float ar = 0.f, ai = 0.f;
#pragma unroll 8
        for (int i = 0; i < 32; i++) {
            float a   = xr[xbase + (size_t)i * 288];
            float bb  = xi[xbase + (size_t)i * 288];
            float wr_ = wp[(size_t)i * 9216];
            float wi_ = wp[(size_t)i * 9216 + 1];
            ar += a * wr_ - bb * wi_;
            ai += a * wi_ + bb * wr_;
        }
        sm_r[m] = ar; sm_i[m] = ai;
    }
    __syncthreads();
    const float* FR = ws + OFF_FR;
    const float* FI = ws + OFF_FI;
    // inv phase 1: A[ky][x] = sum_r M[r][ky] * e^{+i 2pi kx x / 64}  (768 items)
#pragma unroll
    for (int it = 0; it < 2; it++) {
        int point = it * 512 + tid;
        if (point < 768) {
            int x = point & 63;
            int ky = __builtin_amdgcn_readfirstlane(point >> 6);
            float ar = 0.f, ai = 0.f;
#pragma unroll 8
            for (int r = 0; r < 24; r++) {
                float a = sm_r[r * 12 + ky], bb = sm_i[r * 12 + ky];
                float c = FR[r * 64 + x], d = FI[r * 64 + x];   // cos, -sin
                ar += a * c + bb * d;
                ai += bb * c - a * d;
            }
            sa_r[ky * 64 + x] = ar;
            sa_i[ky * 64 + x] = ai;
        }
    }
    __syncthreads();
    float* spb = sp + (size_t)bo * NXY;
    // inv phase 2: c2r over ky — all operands in LDS (4096 px, 8 passes)
#pragma unroll
    for (int it = 0; it < 8; it++) {
        int px = it * 512 + tid;
        int y = px & 63;
        int x = __builtin_amdgcn_readfirstlane(px >> 6);
        float s = sa_r[x];                      // ky=0: Re only
#pragma unroll
        for (int ky = 1; ky < 12; ky++) {
            float gr = sgr[ky * 64 + y];
            float gi = sgi[ky * 64 + y];
            s += 2.0f * (sa_r[ky * 64 + x] * gr + sa_i[ky * 64 + x] * gi);
        }
        spb[px] = s * (1.0f / 4096.0f);
    }
}

// ---------------- K7: 1x1 conv, 2 px per thread, o-split across 2 blocks ----------------
template <int DOGELU>
__global__ void __launch_bounds__(256, 2)
k_convg(const float* __restrict__ sp, const float* __restrict__ hin,
        const float* __restrict__ cwt, const float* __restrict__ cb,
        float* __restrict__ hout) {
    __shared__ __align__(16) float scw[1024];
    __shared__ float scb[32];
    int tid = threadIdx.x;
#pragma unroll
    for (int i = 0; i < 4; i++) scw[tid + 256 * i] = cwt[tid + 256 * i];
    if (tid < 32) scb[tid] = cb[tid];
    __syncthreads();
    int wid = tid >> 6, lane = tid & 63;
    int blk = blockIdx.x;                       // grid = 1024
    int osec = blk & 1;
    int q = (blk >> 1) * 64 + lane;             // pair index 0..32767
    int b = q >> 11, p = (q & 2047) * 2;
    const float* hp = hin + (size_t)b * WID * NXY + p;
    float2 hv[32];
#pragma unroll
    for (int c = 0; c < 32; c++) hv[c] = *(const float2*)(hp + (size_t)c * NXY);
    const float* spp = sp + (size_t)b * WID * NXY + p;
    float* op = hout + (size_t)b * WID * NXY + p;
#pragma unroll
    for (int j = 0; j < 4; j++) {
        int o = osec * 16 + wid * 4 + j;
        const float4* wr = (const float4*)&scw[o * 32];
        float2 d = make_float2(scb[o], scb[o]);
#pragma unroll
        for (int q8 = 0; q8 < 8; q8++) {
            float4 w = wr[q8];
            float2 h0 = hv[q8 * 4], h1 = hv[q8 * 4 + 1], h2 = hv[q8 * 4 + 2], h3 = hv[q8 * 4 + 3];
            d.x += w.x * h0.x + w.y * h1.x + w.z * h2.x + w.w * h3.x;
            d.y += w.x * h0.y + w.y * h1.y + w.z * h2.y + w.w * h3.y;
        }
        float2 spv = *(const float2*)(spp + (size_t)o * NXY);
        float2 v2 = make_float2(d.x + spv.x, d.y + spv.y);
        if (DOGELU) v2 = gelu2(v2);
        *(float2*)(op + (size_t)o * NXY) = v2;
    }
}

// ---------------- K8: fused head, 2 px per thread, e-split across 2 blocks ----------
__global__ void __launch_bounds__(256, 2)
k_head(const float* __restrict__ h, const float* __restrict__ w1t,
       const float* __restrict__ b1, const float* __restrict__ w2,
       float* __restrict__ pt) {
    __shared__ __align__(16) float sw1[64 * 32];
    __shared__ float sb1l[64];
    __shared__ __align__(16) float sw2l[64 * 8];
    __shared__ __align__(8) float2 red[4][6][64];
    int tid = threadIdx.x;
    int blk = blockIdx.x;                       // grid = 1024
    int esec = blk & 1;
    int ebase = esec * 64;
#pragma unroll
    for (int i = 0; i < 8; i++) sw1[tid + 256 * i] = w1t[(size_t)ebase * 32 + tid + 256 * i];
    if (tid < 64) sb1l[tid] = b1[ebase + tid];
    for (int i = tid; i < 384; i += 256) {      // this section's w2 rows -> padded (64x8)
        int e = i / 6, t = i - e * 6;
        sw2l[e * 8 + t] = w2[(size_t)(ebase + e) * 6 + t];
    }
    __syncthreads();
    int wid = tid >> 6, lane = tid & 63;
    int q = (blk >> 1) * 64 + lane;             // pair index 0..32767
    int b = q >> 11, p = (q & 2047) * 2;
    const float* hp = h + (size_t)b * WID * NXY + p;
    float2 hv[32];
#pragma unroll
    for (int c = 0; c < 32; c++) hv[c] = *(const float2*)(hp + (size_t)c * NXY);
    float2 acc[6];
#pragma unroll
    for (int t = 0; t < 6; t++) acc[t] = make_float2(0.f, 0.f);
#pragma unroll 4
    for (int jj = 0; jj < 16; jj++) {
        int el = wid * 16 + jj;                 // local e 0..63
        const float4* wr = (const float4*)&sw1[el * 32];
        float2 d = make_float2(sb1l[el], sb1l[el]);
#pragma unroll
        for (int q8 = 0; q8 < 8; q8++) {
            float4 w = wr[q8];
            float2 h0 = hv[q8 * 4], h1 = hv[q8 * 4 + 1], h2 = hv[q8 * 4 + 2], h3 = hv[q8 * 4 + 3];
            d.x += w.x * h0.x + w.y * h1.x + w.z * h2.x + w.w * h3.x;
            d.y += w.x * h0.y + w.y * h1.y + w.z * h2.y + w.w * h3.y;
        }
        float2 g = gelu2(d);
        const float4* w2r = (const float4*)&sw2l[el * 8];
        float4 wa = w2r[0], wb = w2r[1];
        acc[0].x += g.x * wa.x; acc[0].y += g.y * wa.x;
        acc[1].x += g.x * wa.y; acc[1].y += g.y * wa.y;
        acc[2].x += g.x * wa.z; acc[2].y += g.y * wa.z;
        acc[3].x += g.x * wa.w; acc[3].y += g.y * wa.w;
        acc[4].x += g.x * wb.x; acc[4].y += g.y * wb.x;
        acc[5].x += g.x * wb.y; acc[5].y += g.y * wb.y;
    }
#pragma unroll
    for (int t = 0; t < 6; t++) red[wid][t][lane] = acc[t];
    __syncthreads();
    if (wid == 0) {
        float* pb = pt + (size_t)esec * PT_STRIDE + (size_t)b * 6 * NXY + p;
#pragma unroll
        for (int t = 0; t < 6; t++) {
            float2 r0 = red[0][t][lane], r1 = red[1][t][lane];
            float2 r2 = red[2][t][lane], r3 = red[3][t][lane];
            float2 s = make_float2(r0.x + r1.x + r2.x + r3.x,
                                   r0.y + r1.y + r2.y + r3.y);
            *(float2*)(pb + (size_t)t * NXY) = s;
        }
    }
}

// ---------------- K10: NS update; sums head partials inline (fc2 bias cancels in diffs) ----
__global__ void __launch_bounds__(256, 2)
k_ns(const float* __restrict__ v, const float* __restrict__ pt,
     float* __restrict__ out) {
    int idx = blockIdx.x * 256 + threadIdx.x;   // 4096 blocks
    int b = idx >> 16;
    int r = idx & 65535;
    int x = r >> 10;
    int y = (r >> 4) & 63;
    int z0 = (r & 15) * 4;
    int xp = (x + 1) & 63, xm = (x - 1) & 63;
    int yp = (y + 1) & 63, ym = (y - 1) & 63;
    int zm = (z0 - 1) & 63, zp = (z0 + 4) & 63;

    float4 u[3], gx[3], gy[3], gz[3], lap[3];
    for (int i = 0; i < 3; i++) {
        const float* vb = v + (((size_t)(b * 3 + i)) << 18);
        const float* row = vb + (size_t)x * 4096 + (size_t)y * 64;
        float4 c4   = *(const float4*)(row + z0);
        float  czm  = row[zm];
        float  czp  = row[zp];
        float4 xp4  = *(const float4*)(vb + (size_t)xp * 4096 + (size_t)y * 64 + z0);
        float4 xm4  = *(const float4*)(vb + (size_t)xm * 4096 + (size_t)y * 64 + z0);
        float4 yp4  = *(const float4*)(vb + (size_t)x * 4096 + (size_t)yp * 64 + z0);
        float4 ym4  = *(const float4*)(vb + (size_t)x * 4096 + (size_t)ym * 64 + z0);
        u[i] = c4;
        gx[i] = make_float4((xp4.x - xm4.x) * INV2DX, (xp4.y - xm4.y) * INV2DX,
                            (xp4.z - xm4.z) * INV2DX, (xp4.w - xm4.w) * INV2DX);
        gy[i] = make_float4((yp4.x - ym4.x) * INV2DX, (yp4.y - ym4.y) * INV2DX,
                            (yp4.z - ym4.z) * INV2DX, (yp4.w - ym4.w) * INV2DX);
        gz[i] = make_float4((c4.y - czm) * INV2DX, (c4.z - c4.x) * INV2DX,
                            (c4.w - c4.y) * INV2DX, (czp - c4.z) * INV2DX);
        lap[i] = make_float4(
            (xp4.x + xm4.x + yp4.x + ym4.x + czm  + c4.y - 6.f * c4.x) * INVDX2,
            (xp4.y + xm4.y + yp4.y + ym4.y + c4.x + c4.z - 6.f * c4.y) * INVDX2,
            (xp4.z + xm4.z + yp4.z + ym4.z + c4.y + c4.w - 6.f * c4.z) * INVDX2,
            (xp4.w + xm4.w + yp4.w + ym4.w + c4.z + czp  - 6.f * c4.w) * INVDX2);
    }
    const float* p0 = pt + (size_t)b * 6 * NXY;
    const float* p1 = p0 + PT_STRIDE;
    int pxp = xp * 64 + y, pxm = xm * 64 + y, pyp = x * 64 + yp, pym = x * 64 + ym;
#define TV(t, pos) (p0[(size_t)(t) * NXY + (pos)] + p1[(size_t)(t) * NXY + (pos)])
    float d0 = (TV(0, pxp) - TV(0, pxm)) * INV2DX + (TV(3, pyp) - TV(3, pym)) * INV2DX;
    float d1 = (TV(3, pxp) - TV(3, pxm)) * INV2DX + (TV(1, pyp) - TV(1, pym)) * INV2DX;
    float d2 = (TV(4, pxp) - TV(4, pxm)) * INV2DX + (TV(5, pyp) - TV(5, pym)) * INV2DX;
#undef TV

    size_t so = ((size_t)b * 3) * NVOL + (size_t)x * 4096 + (size_t)y * 64 + z0;
#pragma unroll
    for (int i = 0; i < 3; i++) {
        float dti = (i == 0) ? d0 : (i == 1) ? d1 : d2;
        float4 conv = make_float4(
            u[0].x * ((i==0)?gx[0].x:(i==1)?gy[0].x:gz[0].x) + u[1].x * ((i==0)?gx[1].x:(i==1)?gy[1].x:gz[1].x) + u[2].x * ((i==0)?gx[2].x:(i==1)?gy[2].x:gz[2].x),
            u[0].y * ((i==0)?gx[0].y:(i==1)?gy[0].y:gz[0].y) + u[1].y * ((i==0)?gx[1].y:(i==1)?gy[1].y:gz[1].y) + u[2].y * ((i==0)?gx[2].y:(i==1)?gy[2].y:gz[2].y),
            u[0].z * ((i==0)?gx[0].z:(i==1)?gy[0].z:gz[0].z) + u[1].z * ((i==0)?gx[1].z:(i==1)?gy[1].z:gz[1].z) + u[2].z * ((i==0)?gx[2].z:(i==1)?gy[2].z:gz[2].z),
            u[0].w * ((i==0)?gx[0].w:(i==1)?gy[0].w:gz[0].w) + u[1].w * ((i==0)?gx[1].w:(i==1)?gy[1].w:gz[1].w) + u[2].w * ((i==0)?gx[2].w:(i==1)?gy[2].w:gz[2].w));
        float4 res = make_float4(
            u[i].x + DT_c * (-conv.x + NU_c * lap[i].x + dti),
            u[i].y + DT_c * (-conv.y + NU_c * lap[i].y + dti),
            u[i].z + DT_c * (-conv.z + NU_c * lap[i].z + dti),
            u[i].w + DT_c * (-conv.w + NU_c * lap[i].w + dti));
        *(float4*)(out + so + (size_t)i * NVOL) = res;
    }
}

extern "C" void kernel_launch(void* const* d_in, const int* in_sizes, int n_in,
                              void* d_out, int out_size, void* d_ws, size_t ws_size,
                              hipStream_t stream) {
    const float* vel   = (const float*)d_in[0];
    const float* fc0w  = (const float*)d_in[1];
    const float* fc0b  = (const float*)d_in[2];
    const float* sw1   = (const float*)d_in[3];
    const float* sw2   = (const float*)d_in[4];
    const float* convw = (const float*)d_in[5];
    const float* convb = (const float*)d_in[6];
    const float* fc1w  = (const float*)d_in[7];
    const float* fc1b  = (const float*)d_in[8];
    const float* fc2w  = (const float*)d_in[9];
    float* ws  = (float*)d_ws;
    float* out = (float*)d_out;

    k_setup<<<34, 256, 0, stream>>>(fc1w, convw, fc0w, ws);
    k_clfc0<<<64, 256, 0, stream>>>(vel, ws + OFF_W0T, fc0b, ws + OFF_HA);

    float* hcur  = ws + OFF_HA;
    float* hnext = ws + OFF_HB;
    for (int l = 0; l < 4; l++) {
        const float* wl1 = sw1 + (size_t)l * WID * WID * MM * MM * 2;
        const float* wl2 = sw2 + (size_t)l * WID * WID * MM * MM * 2;
        const float* cwl = ws + OFF_CWT + (size_t)l * 1024;
        const float* cbl = convb + (size_t)l * 32;
        k_fwd<<<1024, 256, 0, stream>>>(hcur, ws, ws + OFF_XR, ws + OFF_XI);
        k_specinv<<<512, 512, 0, stream>>>(ws + OFF_XR, ws + OFF_XI, wl1, wl2, ws, ws + OFF_SP);
        if (l < 3)
            k_convg<1><<<1024, 256, 0, stream>>>(ws + OFF_SP, hcur, cwl, cbl, hnext);
        else
            k_convg<0><<<1024, 256, 0, stream>>>(ws + OFF_SP, hcur, cwl, cbl, hnext);
        float* tmp = hcur; hcur = hnext; hnext = tmp;
    }

    k_head<<<1024, 256, 0, stream>>>(hcur, ws + OFF_W1T, fc1b, fc2w, ws + OFF_PT);
    k_ns<<<4096, 256, 0, stream>>>(vel, ws + OFF_PT, out);
}